// Round 7
// baseline (349.240 us; speedup 1.0000x reference)
//
#include <hip/hip_runtime.h>

#define SEQ 2048
#define EMB 100
#define BOT 5
#define HSIZE 4096          // power of two, >= 2*SEQ for <=50% load factor
#define SPLIT 16            // gather blocks per row (contiguous 128-token chunks)
#define CHUNK (SEQ / SPLIT) // 128 tokens per k2 block
#define K1T 1024

// ---------------- K1: per-row hash histogram + per-token coefficients ----------------
// Determinism: hash slot positions race, but per-key COUNTS are race-invariant
// integers; Z is a fixed-order sum; coef[b,s] is a pure per-token function.
// Also zeroes the per-row completion counters used by k2's fused finisher.
__global__ __launch_bounds__(K1T) void k1_hist(
    const int* __restrict__ x, const float* __restrict__ idf,
    float* __restrict__ coef, int* __restrict__ cnt)
{
    __shared__ int   hkey[HSIZE];
    __shared__ int   hcnt[HSIZE];
    __shared__ float red[K1T / 64];
    __shared__ float zinv;

    const int b = blockIdx.x, tid = threadIdx.x;
    const int lane = tid & 63, wid = tid >> 6;

    if (tid == 0) cnt[b] = 0;
    for (int i = tid; i < HSIZE; i += K1T) { hkey[i] = -1; hcnt[i] = 0; }
    __syncthreads();

    const int* xrow = x + (size_t)b * SEQ;

    int   myslot[SEQ / K1T];
    float myidf[SEQ / K1T];
    float z = 0.0f;
    #pragma unroll
    for (int j = 0; j < SEQ / K1T; ++j) {
        int s   = tid + j * K1T;
        int key = xrow[s];
        float w = idf[key];
        myidf[j] = w;
        z += w;
        unsigned slot = ((unsigned)key * 2654435761u) >> 20;
        for (;;) {
            int prev = atomicCAS(&hkey[slot], -1, key);
            if (prev == -1 || prev == key) { atomicAdd(&hcnt[slot], 1); break; }
            slot = (slot + 1) & (HSIZE - 1);
        }
        myslot[j] = slot;   // canonical slot for this key (unique per key)
    }
    for (int off = 32; off > 0; off >>= 1) z += __shfl_down(z, off);
    if (lane == 0) red[wid] = z;
    __syncthreads();        // also guarantees all inserts complete before count reads
    if (tid == 0) {
        float t = 0.0f;
        #pragma unroll
        for (int i = 0; i < K1T / 64; ++i) t += red[i];
        zinv = 1.0f / t;
    }
    __syncthreads();
    const float iz = zinv;

    #pragma unroll
    for (int j = 0; j < SEQ / K1T; ++j) {
        int s = tid + j * K1T;
        coef[(size_t)b * SEQ + s] = (float)hcnt[myslot[j]] * myidf[j] * iz;
    }
}

// ---------------- K2: chunked gather + fused last-block reduce/MLP ----------------
// Block bx handles row b = bx/SPLIT, tokens [sp*CHUNK, (sp+1)*CHUNK).
// 4 waves; wave w owns 32 tokens, 8 gather streams in flight; lanes 0..49
// hold float2 slices of the 100-dim row. The last block of each row (per-row
// atomic counter) reduces the 16 partials in FIXED order and runs the MLP —
// bit-deterministic regardless of completion order.
__global__ __launch_bounds__(256) void k2_fused(
    const int* __restrict__ x, const float* __restrict__ coef,
    const float* __restrict__ we, float* __restrict__ partial,
    int* __restrict__ cnt,
    const float* __restrict__ fc1w, const float* __restrict__ fc1b,
    const float* __restrict__ fc2w, const float* __restrict__ fc2b,
    float* __restrict__ out)
{
    __shared__ int   skey[CHUNK];
    __shared__ float scoef[CHUNK];
    __shared__ float part[4][EMB];
    __shared__ float doc[EMB];
    __shared__ float hsh[BOT];
    __shared__ int   slast;

    const int bx   = blockIdx.x;
    const int b    = bx >> 4;             // SPLIT == 16
    const int sp   = bx & (SPLIT - 1);
    const int tid  = threadIdx.x;
    const int wave = tid >> 6;
    const int lane = tid & 63;

    if (tid < CHUNK) {
        skey [tid] = x   [(size_t)b * SEQ + sp * CHUNK + tid];
        scoef[tid] = coef[(size_t)b * SEQ + sp * CHUNK + tid];
    }
    __syncthreads();

    if (lane < EMB / 2) {
        float2 a0 = {0,0}, a1 = {0,0}, a2 = {0,0}, a3 = {0,0};
        float2 a4 = {0,0}, a5 = {0,0}, a6 = {0,0}, a7 = {0,0};
        const int t0 = wave * 32;
        #pragma unroll
        for (int it = 0; it < 4; ++it) {
            const int i = t0 + it * 8;
            int   k0 = skey[i+0], k1 = skey[i+1], k2 = skey[i+2], k3 = skey[i+3];
            int   k4 = skey[i+4], k5 = skey[i+5], k6 = skey[i+6], k7 = skey[i+7];
            float c0 = scoef[i+0], c1 = scoef[i+1], c2 = scoef[i+2], c3 = scoef[i+3];
            float c4 = scoef[i+4], c5 = scoef[i+5], c6 = scoef[i+6], c7 = scoef[i+7];
            float2 v0 = ((const float2*)(we + (size_t)k0 * EMB))[lane];
            float2 v1 = ((const float2*)(we + (size_t)k1 * EMB))[lane];
            float2 v2 = ((const float2*)(we + (size_t)k2 * EMB))[lane];
            float2 v3 = ((const float2*)(we + (size_t)k3 * EMB))[lane];
            float2 v4 = ((const float2*)(we + (size_t)k4 * EMB))[lane];
            float2 v5 = ((const float2*)(we + (size_t)k5 * EMB))[lane];
            float2 v6 = ((const float2*)(we + (size_t)k6 * EMB))[lane];
            float2 v7 = ((const float2*)(we + (size_t)k7 * EMB))[lane];
            a0.x += c0 * v0.x; a0.y += c0 * v0.y;
            a1.x += c1 * v1.x; a1.y += c1 * v1.y;
            a2.x += c2 * v2.x; a2.y += c2 * v2.y;
            a3.x += c3 * v3.x; a3.y += c3 * v3.y;
            a4.x += c4 * v4.x; a4.y += c4 * v4.y;
            a5.x += c5 * v5.x; a5.y += c5 * v5.y;
            a6.x += c6 * v6.x; a6.y += c6 * v6.y;
            a7.x += c7 * v7.x; a7.y += c7 * v7.y;
        }
        float sx = ((a0.x + a1.x) + (a2.x + a3.x)) + ((a4.x + a5.x) + (a6.x + a7.x));
        float sy = ((a0.y + a1.y) + (a2.y + a3.y)) + ((a4.y + a5.y) + (a6.y + a7.y));
        part[wave][2 * lane]     = sx;
        part[wave][2 * lane + 1] = sy;
    }
    __syncthreads();
    if (tid < EMB)
        partial[(size_t)bx * EMB + tid] =
            (part[0][tid] + part[1][tid]) + (part[2][tid] + part[3][tid]);

    // ---- completion protocol: release partials, bump per-row counter ----
    __threadfence();                       // release (all threads)
    __syncthreads();
    if (tid == 0) slast = (atomicAdd(&cnt[b], 1) == SPLIT - 1) ? 1 : 0;
    __syncthreads();
    if (!slast) return;
    __threadfence();                       // acquire (remaining threads)

    // ---- last block of row b: fixed-order reduce + tiny MLP ----
    if (tid < EMB) {
        float a = 0.0f;
        const float* p = partial + (size_t)b * SPLIT * EMB + tid;
        #pragma unroll
        for (int s = 0; s < SPLIT; ++s) a += p[s * EMB];
        doc[tid] = a;
    }
    __syncthreads();

    if (tid < BOT) {
        float h = fc1b[tid];
        const float* wr = fc1w + tid * EMB;
        for (int e = 0; e < EMB; ++e) h += doc[e] * wr[e];
        hsh[tid] = h;
    }
    __syncthreads();

    if (tid < EMB) {
        float o = fc2b[tid];
        const float* wr = fc2w + tid * BOT;
        #pragma unroll
        for (int j = 0; j < BOT; ++j) o += hsh[j] * wr[j];
        out[(size_t)b * EMB + tid] = o;
    }
}

extern "C" void kernel_launch(void* const* d_in, const int* in_sizes, int n_in,
                              void* d_out, int out_size, void* d_ws, size_t ws_size,
                              hipStream_t stream) {
    const int*   x    = (const int*)d_in[0];
    const float* we   = (const float*)d_in[1];
    const float* idf  = (const float*)d_in[2];
    const float* fc1w = (const float*)d_in[3];
    const float* fc1b = (const float*)d_in[4];
    const float* fc2w = (const float*)d_in[5];
    const float* fc2b = (const float*)d_in[6];
    float*       out  = (float*)d_out;

    const int B = in_sizes[0] / SEQ;  // 128

    char* ws = (char*)d_ws;
    float* coef    = (float*)ws;                              // B*SEQ floats (1 MB)
    float* partial = (float*)(ws + (size_t)B * SEQ * 4);      // B*SPLIT*EMB floats
    int*   cnt     = (int*)(ws + (size_t)B * SEQ * 4
                               + (size_t)B * SPLIT * EMB * 4); // B ints

    k1_hist <<<B,         K1T, 0, stream>>>(x, idf, coef, cnt);
    k2_fused<<<B * SPLIT, 256, 0, stream>>>(x, coef, we, partial, cnt,
                                            fc1w, fc1b, fc2w, fc2b, out);
}

// Round 8
// 97.835 us; speedup vs baseline: 3.5697x; 3.5697x over previous
//
#include <hip/hip_runtime.h>

#define SEQ 2048
#define EMB 100
#define BOT 5
#define HSIZE 4096          // power of two, 2*SEQ slots for <=50% load factor
#define RSPLIT 2            // blocks per row
#define HALFN (SEQ / RSPLIT)// 1024 tokens gathered per block
#define FT 1024             // threads per fused block (16 waves)

// ---------------- kA: fused hash-histogram + half-row gather ----------------
// Two blocks per row. Each builds the FULL row histogram in LDS (redundant x2,
// but every CU does exactly one histogram -> wall time halves vs 128-block k1),
// computes Z in fixed order (bit-identical in both blocks), then gathers its
// own half of the tokens and writes a 100-float partial. No device fences.
// Determinism: per-key counts are race-invariant; Z and all float sums are
// fixed-order; coef is a pure per-token function.
__global__ __launch_bounds__(FT) void kA_fused(
    const int* __restrict__ x, const float* __restrict__ idf,
    const float* __restrict__ we, float* __restrict__ partial)
{
    __shared__ int   hkey[HSIZE];
    __shared__ int   hcnt[HSIZE];
    __shared__ int   skey[SEQ];
    __shared__ float scoef[HALFN];
    __shared__ float part[FT / 64][EMB];
    __shared__ float red[FT / 64];
    __shared__ float zinv;

    const int bx   = blockIdx.x;
    const int b    = bx >> 1;
    const int half = bx & 1;
    const int tid  = threadIdx.x;
    const int lane = tid & 63, wid = tid >> 6;

    for (int i = tid; i < HSIZE; i += FT) { hkey[i] = -1; hcnt[i] = 0; }
    for (int i = tid; i < SEQ; i += FT) skey[i] = x[(size_t)b * SEQ + i];
    __syncthreads();

    // two tokens per thread; issue idf loads together for ILP
    const int k0 = skey[tid], k1 = skey[tid + FT];
    const float w0 = idf[k0], w1 = idf[k1];
    float z = w0 + w1;

    unsigned slot0 = ((unsigned)k0 * 2654435761u) >> 20;
    for (;;) {
        int prev = atomicCAS(&hkey[slot0], -1, k0);
        if (prev == -1 || prev == k0) { atomicAdd(&hcnt[slot0], 1); break; }
        slot0 = (slot0 + 1) & (HSIZE - 1);
    }
    unsigned slot1 = ((unsigned)k1 * 2654435761u) >> 20;
    for (;;) {
        int prev = atomicCAS(&hkey[slot1], -1, k1);
        if (prev == -1 || prev == k1) { atomicAdd(&hcnt[slot1], 1); break; }
        slot1 = (slot1 + 1) & (HSIZE - 1);
    }

    // fixed-order Z reduction (identical bits in both blocks of the row)
    for (int off = 32; off > 0; off >>= 1) z += __shfl_down(z, off);
    if (lane == 0) red[wid] = z;
    __syncthreads();                  // also: all inserts complete before reads
    if (tid == 0) {
        float t = 0.0f;
        #pragma unroll
        for (int i = 0; i < FT / 64; ++i) t += red[i];
        zinv = 1.0f / t;
    }
    __syncthreads();
    const float iz = zinv;

    // coef for THIS block's gather token (tid within the half): tokens
    // {tid, tid+1024} belong to this thread; the gather token half*1024+tid
    // is one of them -> reuse memoized slot and idf, no re-probe.
    {
        const int      myslot = half ? (int)slot1 : (int)slot0;
        const float    myw    = half ? w1 : w0;
        scoef[tid] = (float)hcnt[myslot] * myw * iz;
    }
    __syncthreads();

    // gather: wave w owns local tokens [w*64, w*64+64), 8 streams in flight;
    // lanes 0..49 hold float2 slices of the 100-dim embedding row.
    if (lane < EMB / 2) {
        float2 a0 = {0,0}, a1 = {0,0}, a2 = {0,0}, a3 = {0,0};
        float2 a4 = {0,0}, a5 = {0,0}, a6 = {0,0}, a7 = {0,0};
        const int base = half * HALFN + wid * 64;
        const int cb   = wid * 64;
        #pragma unroll
        for (int it = 0; it < 8; ++it) {
            const int i = it * 8;
            int   t0 = skey[base+i+0], t1 = skey[base+i+1], t2 = skey[base+i+2], t3 = skey[base+i+3];
            int   t4 = skey[base+i+4], t5 = skey[base+i+5], t6 = skey[base+i+6], t7 = skey[base+i+7];
            float c0 = scoef[cb+i+0], c1 = scoef[cb+i+1], c2 = scoef[cb+i+2], c3 = scoef[cb+i+3];
            float c4 = scoef[cb+i+4], c5 = scoef[cb+i+5], c6 = scoef[cb+i+6], c7 = scoef[cb+i+7];
            float2 v0 = ((const float2*)(we + (size_t)t0 * EMB))[lane];
            float2 v1 = ((const float2*)(we + (size_t)t1 * EMB))[lane];
            float2 v2 = ((const float2*)(we + (size_t)t2 * EMB))[lane];
            float2 v3 = ((const float2*)(we + (size_t)t3 * EMB))[lane];
            float2 v4 = ((const float2*)(we + (size_t)t4 * EMB))[lane];
            float2 v5 = ((const float2*)(we + (size_t)t5 * EMB))[lane];
            float2 v6 = ((const float2*)(we + (size_t)t6 * EMB))[lane];
            float2 v7 = ((const float2*)(we + (size_t)t7 * EMB))[lane];
            a0.x += c0 * v0.x; a0.y += c0 * v0.y;
            a1.x += c1 * v1.x; a1.y += c1 * v1.y;
            a2.x += c2 * v2.x; a2.y += c2 * v2.y;
            a3.x += c3 * v3.x; a3.y += c3 * v3.y;
            a4.x += c4 * v4.x; a4.y += c4 * v4.y;
            a5.x += c5 * v5.x; a5.y += c5 * v5.y;
            a6.x += c6 * v6.x; a6.y += c6 * v6.y;
            a7.x += c7 * v7.x; a7.y += c7 * v7.y;
        }
        float sx = ((a0.x + a1.x) + (a2.x + a3.x)) + ((a4.x + a5.x) + (a6.x + a7.x));
        float sy = ((a0.y + a1.y) + (a2.y + a3.y)) + ((a4.y + a5.y) + (a6.y + a7.y));
        part[wid][2 * lane]     = sx;
        part[wid][2 * lane + 1] = sy;
    }
    __syncthreads();
    if (tid < EMB) {
        float a = 0.0f;
        #pragma unroll
        for (int w = 0; w < FT / 64; ++w) a += part[w][tid];   // fixed order
        partial[(size_t)bx * EMB + tid] = a;
    }
}

// ---------------- kB: reduce 2 partials + tiny MLP ----------------
__global__ __launch_bounds__(128) void kB_mlp(
    const float* __restrict__ partial,
    const float* __restrict__ fc1w, const float* __restrict__ fc1b,
    const float* __restrict__ fc2w, const float* __restrict__ fc2b,
    float* __restrict__ out)
{
    __shared__ float doc[EMB];
    __shared__ float hsh[BOT];

    const int b = blockIdx.x, tid = threadIdx.x;

    if (tid < EMB) {
        const float* p = partial + (size_t)b * RSPLIT * EMB + tid;
        doc[tid] = p[0] + p[EMB];          // fixed order
    }
    __syncthreads();

    if (tid < BOT) {
        float h = fc1b[tid];
        const float* wr = fc1w + tid * EMB;
        for (int e = 0; e < EMB; ++e) h += doc[e] * wr[e];
        hsh[tid] = h;
    }
    __syncthreads();

    if (tid < EMB) {
        float o = fc2b[tid];
        const float* wr = fc2w + tid * BOT;
        #pragma unroll
        for (int j = 0; j < BOT; ++j) o += hsh[j] * wr[j];
        out[(size_t)b * EMB + tid] = o;
    }
}

extern "C" void kernel_launch(void* const* d_in, const int* in_sizes, int n_in,
                              void* d_out, int out_size, void* d_ws, size_t ws_size,
                              hipStream_t stream) {
    const int*   x    = (const int*)d_in[0];
    const float* we   = (const float*)d_in[1];
    const float* idf  = (const float*)d_in[2];
    const float* fc1w = (const float*)d_in[3];
    const float* fc1b = (const float*)d_in[4];
    const float* fc2w = (const float*)d_in[5];
    const float* fc2b = (const float*)d_in[6];
    float*       out  = (float*)d_out;

    const int B = in_sizes[0] / SEQ;  // 128

    float* partial = (float*)d_ws;    // B*RSPLIT*EMB floats (~102 KB)

    kA_fused<<<B * RSPLIT, FT,  0, stream>>>(x, idf, we, partial);
    kB_mlp  <<<B,          128, 0, stream>>>(partial, fc1w, fc1b, fc2w, fc2b, out);
}